// Round 1
// baseline (22.632 us; speedup 1.0000x reference)
//
#include <hip/hip_runtime.h>
#include <cmath>

constexpr int Bn = 2, Hn = 256, Wn = 256, Cn = 2;

__global__ __launch_bounds__(256, 2) void sinc_warp_kernel(
    const float* __restrict__ img, const float* __restrict__ fmap,
    float* __restrict__ out)
{
    // float32(np.pi) exactly
    const float PI_F = 0x1.921fb6p+1f;
    // TF quirk: x==0 replaced by 1.0 BEFORE sin(pi*x)/(pi*x) -> sinf(PI_F)/PI_F
    const float C0 = -2.7827531e-8f;

    __shared__ float sh_img[Hn][Cn];
    __shared__ float sh_s  [Hn][Cn];  // sin(pi * x0), sign included
    __shared__ float sh_x  [Hn][Cn];  // x0 = clip(fmap + i, 0, H-1)

    const int bw = blockIdx.x;
    const int b  = bw >> 8;   // / Wn
    const int w  = bw & 255;  // % Wn
    const int t  = threadIdx.x;

    // Stage + precompute: thread t owns input row i = t (both channels).
    {
        const int i = t;
        const size_t base = (((size_t)b * Hn + i) * Wn + w) * Cn;
#pragma unroll
        for (int c = 0; c < Cn; ++c) {
            const float f  = fmap[base + c];
            float x0 = fminf(fmaxf(f + (float)i, 0.0f), (float)(Hn - 1));
            const float n = rintf(x0);          // nearest integer, x0 >= 0
            float s = sinf(PI_F * (x0 - n));    // |arg| <= pi/2, accurate
            if (((int)n) & 1) s = -s;           // s = sin(pi * x0)
            sh_img[i][c] = img[base + c];
            sh_s  [i][c] = s;
            sh_x  [i][c] = x0;
        }
    }
    __syncthreads();

    // Thread j computes out[b, j, w, 0..1].
    const int j = t;
    const float jf  = (float)j;
    // (-1)^j folded out of the loop; pre-flip the d==0 constant so the
    // final sign multiply restores it to +C0.
    const float c0j = (j & 1) ? -C0 : C0;
    float acc0 = 0.0f, acc1 = 0.0f;

#pragma unroll 8
    for (int i = 0; i < Hn; ++i) {
        const float d0 = sh_x[i][0] - jf;   // exact fp32, matches ref's diff
        const float d1 = sh_x[i][1] - jf;
        float v0 = sh_s[i][0] * __builtin_amdgcn_rcpf(PI_F * d0);
        float v1 = sh_s[i][1] * __builtin_amdgcn_rcpf(PI_F * d1);
        v0 = (d0 == 0.0f) ? c0j : v0;       // TF x==0 quirk
        v1 = (d1 == 0.0f) ? c0j : v1;
        acc0 = fmaf(sh_img[i][0], v0, acc0);
        acc1 = fmaf(sh_img[i][1], v1, acc1);
    }

    const float sgn = (j & 1) ? -1.0f : 1.0f;
    const size_t obase = (((size_t)b * Hn + j) * Wn + w) * Cn;
    out[obase + 0] = sgn * acc0;
    out[obase + 1] = sgn * acc1;
}

extern "C" void kernel_launch(void* const* d_in, const int* in_sizes, int n_in,
                              void* d_out, int out_size, void* d_ws, size_t ws_size,
                              hipStream_t stream)
{
    (void)in_sizes; (void)n_in; (void)out_size; (void)d_ws; (void)ws_size;
    const float* img  = (const float*)d_in[0];
    const float* fmap = (const float*)d_in[1];
    float* out = (float*)d_out;
    sinc_warp_kernel<<<Bn * Wn, 256, 0, stream>>>(img, fmap, out);
}

// Round 2
// 19.744 us; speedup vs baseline: 1.1463x; 1.1463x over previous
//
#include <hip/hip_runtime.h>
#include <cmath>

constexpr int Bn = 2, Hn = 256, Wn = 256, Cn = 2;

__global__ __launch_bounds__(256, 2) void sinc_warp_kernel(
    const float* __restrict__ img, const float* __restrict__ fmap,
    float* __restrict__ out)
{
    const float INV_PI = 0x1.45f306p-2f;     // float32(1/pi)
    // TF quirk: x==0 replaced by 1.0 BEFORE sin(pi*x)/(pi*x) -> sinf(PI_F)/PI_F
    const float C0 = -2.7827531e-8f;

    // Staged per (i, c): x0, sin(pi*x0)/pi, img. Packed [i][c] so a float4
    // covers 2 i's x 2 channels -> ds_read_b128.
    __shared__ __align__(16) float sh_x [Hn * Cn];
    __shared__ __align__(16) float sh_sp[Hn * Cn];
    __shared__ __align__(16) float sh_im[Hn * Cn];
    __shared__ __align__(16) float sh_acc[4][Hn * Cn];   // partials per i-chunk

    const int bw = blockIdx.x;
    const int b  = bw >> 8;   // / Wn
    const int w  = bw & 255;  // % Wn
    const int t  = threadIdx.x;

    // Stage + precompute: thread t owns input row i = t (both channels).
    {
        const int i = t;
        const size_t base = (((size_t)b * Hn + i) * Wn + w) * Cn;
#pragma unroll
        for (int c = 0; c < Cn; ++c) {
            const float f  = fmap[base + c];
            float x0 = fminf(fmaxf(f + (float)i, 0.0f), (float)(Hn - 1));
            const float n = rintf(x0);          // x0 >= 0
            const float r = x0 - n;             // r in [-0.5, 0.5]
            // sin(pi*r) via v_sin_f32 (input in revolutions): sin(2*pi*(r/2))
            float sp = __builtin_amdgcn_sinf(0.5f * r) * INV_PI;
            if (((int)n) & 1) sp = -sp;         // sp = sin(pi*x0)/pi
            sh_x [i * Cn + c] = x0;
            sh_sp[i * Cn + c] = sp;
            sh_im[i * Cn + c] = img[base + c];
        }
    }
    __syncthreads();

    // Compute: thread (ig, jl) accumulates i in [ig*64, ig*64+64) for
    // j in {jl, jl+64, jl+128, jl+192}, both channels.
    const int ig = t >> 6;
    const int jl = t & 63;
    // (-1)^j folded out of the loop (parity of j == parity of jl).
    const float c0j = (jl & 1) ? -C0 : C0;

    float jf[4];
#pragma unroll
    for (int jj = 0; jj < 4; ++jj) jf[jj] = (float)(jl + 64 * jj);

    float acc[4][2];
#pragma unroll
    for (int jj = 0; jj < 4; ++jj) { acc[jj][0] = 0.0f; acc[jj][1] = 0.0f; }

    const float4* px  = (const float4*)sh_x;
    const float4* psp = (const float4*)sh_sp;
    const float4* pim = (const float4*)sh_im;

    const int k0 = ig * 32;   // 64 i's = 32 float4 groups
#pragma unroll 4
    for (int k = 0; k < 32; ++k) {
        const float4 xv  = px [k0 + k];   // {x[2k][0], x[2k][1], x[2k+1][0], x[2k+1][1]}
        const float4 spv = psp[k0 + k];
        const float4 imv = pim[k0 + k];
#pragma unroll
        for (int jj = 0; jj < 4; ++jj) {
            const float J = jf[jj];
            {   const float d = xv.x - J;
                float v = spv.x * __builtin_amdgcn_rcpf(d);
                v = (d == 0.0f) ? c0j : v;
                acc[jj][0] = fmaf(imv.x, v, acc[jj][0]); }
            {   const float d = xv.y - J;
                float v = spv.y * __builtin_amdgcn_rcpf(d);
                v = (d == 0.0f) ? c0j : v;
                acc[jj][1] = fmaf(imv.y, v, acc[jj][1]); }
            {   const float d = xv.z - J;
                float v = spv.z * __builtin_amdgcn_rcpf(d);
                v = (d == 0.0f) ? c0j : v;
                acc[jj][0] = fmaf(imv.z, v, acc[jj][0]); }
            {   const float d = xv.w - J;
                float v = spv.w * __builtin_amdgcn_rcpf(d);
                v = (d == 0.0f) ? c0j : v;
                acc[jj][1] = fmaf(imv.w, v, acc[jj][1]); }
        }
    }

    // Write partials, reduce across the 4 i-chunks.
#pragma unroll
    for (int jj = 0; jj < 4; ++jj) {
        const int j = jl + 64 * jj;
        sh_acc[ig][j * 2 + 0] = acc[jj][0];
        sh_acc[ig][j * 2 + 1] = acc[jj][1];
    }
    __syncthreads();
    {
        const int j = t;
        float a0 = 0.0f, a1 = 0.0f;
#pragma unroll
        for (int g = 0; g < 4; ++g) {
            a0 += sh_acc[g][j * 2 + 0];
            a1 += sh_acc[g][j * 2 + 1];
        }
        const float sgn = (j & 1) ? -1.0f : 1.0f;
        const size_t obase = (((size_t)b * Hn + j) * Wn + w) * Cn;
        out[obase + 0] = sgn * a0;
        out[obase + 1] = sgn * a1;
    }
}

extern "C" void kernel_launch(void* const* d_in, const int* in_sizes, int n_in,
                              void* d_out, int out_size, void* d_ws, size_t ws_size,
                              hipStream_t stream)
{
    (void)in_sizes; (void)n_in; (void)out_size; (void)d_ws; (void)ws_size;
    const float* img  = (const float*)d_in[0];
    const float* fmap = (const float*)d_in[1];
    float* out = (float*)d_out;
    sinc_warp_kernel<<<Bn * Wn, 256, 0, stream>>>(img, fmap, out);
}